// Round 17
// baseline (283.624 us; speedup 1.0000x reference)
//
#include <hip/hip_runtime.h>
#include <math.h>
#include <limits.h>

// RelativeBucketedTimeAndPositionBasedBias — B=16, N=2048, NUM_BUCKETS=128
// out[b,i,j] = pos_w[N-1 + j - i] + ts_w[bucket(b,i,j)]
//   diff = ext[b,i+1] - ext[b,j]; m = max(|diff·causal|, 1)  (integer, < 2^24)
//
// VERIFIED BIT-EXACT (R12-R16, absmax=0): ref pipeline is
//   bucket = clip(trunc( RN_f32( log32(m) * RN_f32(1/0.301f) ) ), 0, 128)
// realized as bucket(m) = max{ k : T[k] <= m } via exact integer thresholds T.
// Init formula (hw __log2f estimate +-1, corrected by s_T compares) verified
// bit-exact in R13. DO NOT alter the T pipeline.
//
// R17 perf: R13-R16 all kept ~2 LDS instrs/element and all plateaued at main
// ~66-76 us (vs 41 us store floor) — LDS pipe (~65k cyc/CU) is the limiter.
// Monotone-walk restructure: per column j (fixed per thread across the block's
// 16 rows), m(r) = max(t_next(r)-ts[j],1) is NON-DECREASING in r, so bucket is
// non-decreasing. Init (b, T[b+1], w[b]) once into REGISTERS, then per row:
// one compare; on rare crossings, masked b32 reads advance the state. Steady
// state: ~7 VALU + 0 LDS per element. Non-causal columns clamp m=1 (b parks
// at 0) until they turn causal; output select handles j>i -> ts_w[0].

#define NN 2048
#define BLOCK 256
#define ROWS 16
#define NTHR 130   // thresholds T[0..129]

__global__ void build_thresholds_kernel(int* __restrict__ T) {
    const int k = blockIdx.x;              // 0..129
    __shared__ int s_min;
    if (threadIdx.x == 0) s_min = INT_MAX;
    __syncthreads();

    const float recip = (float)(1.0 / (double)0.301f);   // RN_f32(1/f32(0.301))
    const double est = exp(0.301 * (double)k);
    if (est > 2.0e9) {
        if (threadIdx.x == 0) T[k] = INT_MAX;
        return;
    }
    long long lo = (long long)floor(est) - 256;
    if (lo < 1) lo = 1;
    const long long m = lo + (long long)threadIdx.x;     // one candidate/thread
    const float lg = (float)log((double)m);              // CR f32 log of integer m
    const float q = lg * recip;                          // f32 RN multiply
    if ((int)q >= k) atomicMin(&s_min, (int)m);          // monotone predicate
    __syncthreads();
    if (threadIdx.x == 0) T[k] = s_min;
}

__global__ __launch_bounds__(BLOCK, 4) void hstu_bias_kernel(
    const int* __restrict__ ts,       // [B, N] int32, sorted per row
    const float* __restrict__ ts_w,   // [129]
    const float* __restrict__ pos_w,  // [2N-1]
    const int* __restrict__ T,        // [130] exact thresholds
    float* __restrict__ out)          // [B, N, N]
{
    __shared__ int s_T[NTHR];         // T[0..129]; T[129] = INT_MAX (guard)
    __shared__ float s_tsw[129];
    __shared__ int s_tnext[ROWS];
    const int tid = threadIdx.x;

    const int grp = blockIdx.x;          // 0..2047
    const int bb_ = grp >> 7;            // batch b
    const int i0 = (grp & 127) << 4;     // first row
    const int* __restrict__ ts_row = ts + bb_ * NN;

    if (tid < NTHR) s_T[tid] = T[tid];
    if (tid < 129) s_tsw[tid] = ts_w[tid];
    if (tid < ROWS) {
        const int i = i0 + tid;
        s_tnext[tid] = ts_row[(i < NN - 1) ? (i + 1) : (NN - 1)];  // ext[b,i+1]
    }

    const int j_0 = tid * 4;
    const int j_1 = tid * 4 + 1024;
    const int4 tj0 = *(const int4*)(ts_row + j_0);   // columns cached in regs
    const int4 tj1 = *(const int4*)(ts_row + j_1);

    __syncthreads();
    const float ts0 = s_tsw[0];

    int  tj[8] = {tj0.x, tj0.y, tj0.z, tj0.w, tj1.x, tj1.y, tj1.z, tj1.w};
    int  dj[8];                        // j - i0 (causal when dj <= r)
#pragma unroll
    for (int x = 0; x < 8; ++x) dj[x] = ((x < 4) ? (j_0 + x) : (j_1 + x - 4)) - i0;

    int bkt[8], Tn[8];
    float ww[8];
    {   // exact init from row 0 (R13-verified formula), state into registers
        const int tn = s_tnext[0];
#pragma unroll
        for (int x = 0; x < 8; ++x) {
            int mi = tn - tj[x];
            mi = mi < 1 ? 1 : mi;
            int b0 = (int)(__log2f((float)mi) * 2.3028146f);
            b0 = b0 < 0 ? 0 : (b0 > 128 ? 128 : b0);
            const int bx = b0 + (mi >= s_T[b0 + 1] ? 1 : 0) - (mi < s_T[b0] ? 1 : 0);
            bkt[x] = bx;
            ww[x] = s_tsw[bx];
            Tn[x] = s_T[bx + 1];       // bx <= 128 -> s_T[129] guard = INT_MAX
        }
    }

    float* __restrict__ out_base = out + (size_t)(bb_ * NN + i0) * NN;

#pragma unroll 2
    for (int r = 0; r < ROWS; ++r) {
        const int tn = s_tnext[r];
        const float* __restrict__ pw = pos_w + (NN - 1 - (i0 + r));
        float4* __restrict__ out4 = (float4*)(out_base + (size_t)r * NN);

        float4 pva, pvb;                         // 4B-aligned 16B global loads
        __builtin_memcpy(&pva, pw + j_0, 16);
        __builtin_memcpy(&pvb, pw + j_1, 16);

        float vals[8];
#pragma unroll
        for (int x = 0; x < 8; ++x) {
            int mi = tn - tj[x];
            mi = mi < 1 ? 1 : mi;                // m non-decreasing in r
            while (mi >= Tn[x]) {                // rare: bucket crossing
                ++bkt[x];
                ww[x] = s_tsw[bkt[x]];
                Tn[x] = s_T[bkt[x] + 1];
            }
            vals[x] = (dj[x] <= r) ? ww[x] : ts0;   // causal select
        }

        float4 ra, rb;
        ra.x = pva.x + vals[0];  ra.y = pva.y + vals[1];
        ra.z = pva.z + vals[2];  ra.w = pva.w + vals[3];
        rb.x = pvb.x + vals[4];  rb.y = pvb.y + vals[5];
        rb.z = pvb.z + vals[6];  rb.w = pvb.w + vals[7];

        out4[tid] = ra;
        out4[tid + 256] = rb;
    }
}

extern "C" void kernel_launch(void* const* d_in, const int* in_sizes, int n_in,
                              void* d_out, int out_size, void* d_ws, size_t ws_size,
                              hipStream_t stream) {
    const int* ts = (const int*)d_in[0];        // all_timestamps [16,2048]
    const float* ts_w = (const float*)d_in[1];  // [129]
    const float* pos_w = (const float*)d_in[2]; // [4095]
    float* out = (float*)d_out;                 // [16,2048,2048] f32
    int* T = (int*)d_ws;                        // [130] at ws+0

    build_thresholds_kernel<<<dim3(NTHR), dim3(512), 0, stream>>>(T);

    const int B = 16;
    hstu_bias_kernel<<<dim3(B * NN / ROWS), dim3(BLOCK), 0, stream>>>(
        ts, ts_w, pos_w, T, out);
}